// Round 8
// baseline (91.195 us; speedup 1.0000x reference)
//
#include <hip/hip_runtime.h>

// CRF loss on MI355X.
//   Z-part: exp-domain forward algorithm. exp(step matrix) = diag(g_t)*E with
//   g_t[i]=exp(sigmoid(h[t,b,i])), E=exp(trans)*2^-4 (corrected by 4*ln2*len
//   at the end). L=1024 in 16 chunks of 64 steps.
//   Phase 1 (R8 = R7 fixed): wave owns chunks (c, c+8) of one b. The ENTIRE
//   64-step dual-chain loop is ONE raw asm block with fixed registers
//   v32-v61: no per-step operand marshaling (R1-R6 post-mortem: VALUBusy
//   implies ~3x source-visible VALU -> compiler marshaling around per-step
//   asm). R8 fixes: loop counts go through readfirstlane (R7's "+s" on a
//   VGPR-derived value -> illegal VGPR->SGPR copy), s_nop 4 -> s_nop 6 to
//   match the R1-proven 17-cycle MFMA->VALU-read distance.
//   Phase 2: one wave per b combines 16 chunk matrices (power-of-2 renorm).
//   S-part: gather-sum of trans[y0[t+1],y0[t]]*mask[t].
// ws layout: [0,8KB) len, [8KB,16KB) S, [16KB,+16MB) P bf16.

typedef unsigned int u32;
typedef float f32x4 __attribute__((ext_vector_type(4)));
typedef short s16x4 __attribute__((ext_vector_type(4)));
typedef unsigned int u32x2 __attribute__((ext_vector_type(2)));

#define LOG2E 1.4426950408889634f
#define LN2   0.6931471805599453f
#define Bsz   2048
#define Lsz   1024
#define BT    32768   /* Bsz*16 floats per timestep */

#if __has_builtin(__builtin_amdgcn_exp2f)
__device__ __forceinline__ float exp2x(float x){ return __builtin_amdgcn_exp2f(x); }
#else
__device__ __forceinline__ float exp2x(float x){ return exp2f(x); }
#endif
#if __has_builtin(__builtin_amdgcn_logf)
__device__ __forceinline__ float log2x(float x){ return __builtin_amdgcn_logf(x); }
#else
__device__ __forceinline__ float log2x(float x){ return log2f(x); }
#endif
#if __has_builtin(__builtin_amdgcn_rcpf)
__device__ __forceinline__ float rcpx(float x){ return __builtin_amdgcn_rcpf(x); }
#else
__device__ __forceinline__ float rcpx(float x){ return 1.0f/x; }
#endif

__device__ __forceinline__ u32 cvtpk_bf16(float lo, float hi){
  u32 r;
  asm("v_cvt_pk_bf16_f32 %0, %1, %2" : "=v"(r) : "v"(lo), "v"(hi));
  return r;
}

// R1-proven single MFMA with hazard padding (odd-tail step only).
__device__ __forceinline__ f32x4 mfma16(s16x4 a, s16x4 b, f32x4 c){
  f32x4 d;
  asm volatile("s_nop 1\n\t"
      "v_mfma_f32_16x16x16_bf16 %0, %1, %2, %3\n\t"
      "s_nop 7\n\t"
      "s_nop 7"
      : "=&v"(d) : "v"(a), "v"(b), "v"(c));
  return d;
}

// Whole dual-chain K-loop, fixed regs. Registers:
//  v[32:35] d0, v[36:39] d1, v[40:41] B0, v[42:43] B1, v[44:47] g0 raw,
//  v[48:51] g1 raw, v[52:55] unpack scratch, v[56:57] EA, v[58:61] zero C.
// Per iter: 2 steps of each chain (one b128 = 2 steps' g for own 4 rows).
// Hazards: lgkmcnt(0) before unpack; VALU->MFMA s_nop 1 (2 wait states);
// MFMA-issue -> dest-read distance 17 cyc (1 MFMA + 8 unpack-VALU + s_nop 6).
#define RUN_SEG(CNT, A0, A1, B0X, B0Y, B1X, B1Y, ELO, EHI)                     \
  asm volatile(                                                                \
    "s_waitcnt lgkmcnt(0)\n\t"                                                 \
    "v_mov_b32 v40, %[b0x]\n\t"                                                \
    "v_mov_b32 v41, %[b0y]\n\t"                                                \
    "v_mov_b32 v42, %[b1x]\n\t"                                                \
    "v_mov_b32 v43, %[b1y]\n\t"                                                \
    "v_mov_b32 v56, %[elo]\n\t"                                                \
    "v_mov_b32 v57, %[ehi]\n\t"                                                \
    "v_mov_b32 v58, 0\n\t"                                                     \
    "v_mov_b32 v59, 0\n\t"                                                     \
    "v_mov_b32 v60, 0\n\t"                                                     \
    "v_mov_b32 v61, 0\n\t"                                                     \
    ".LP%=:\n\t"                                                               \
    "ds_read_b128 v[44:47], %[a0]\n\t"                                         \
    "ds_read_b128 v[48:51], %[a1]\n\t"                                         \
    "v_add_u32 %[a0], 16, %[a0]\n\t"                                           \
    "v_add_u32 %[a1], 16, %[a1]\n\t"                                           \
    "s_waitcnt lgkmcnt(0)\n\t"                                                 \
    "s_nop 1\n\t"                                                              \
    "v_mfma_f32_16x16x16_bf16 v[32:35], v[56:57], v[40:41], v[58:61]\n\t"      \
    "v_mfma_f32_16x16x16_bf16 v[36:39], v[56:57], v[42:43], v[58:61]\n\t"      \
    "v_lshlrev_b32 v52, 16, v44\n\t"                                           \
    "v_and_b32 v53, 0xffff0000, v44\n\t"                                       \
    "v_lshlrev_b32 v54, 16, v45\n\t"                                           \
    "v_and_b32 v55, 0xffff0000, v45\n\t"                                       \
    "s_nop 6\n\t"                                                              \
    "v_mul_f32 v52, v32, v52\n\t"                                              \
    "v_mul_f32 v53, v33, v53\n\t"                                              \
    "v_mul_f32 v54, v34, v54\n\t"                                              \
    "v_mul_f32 v55, v35, v55\n\t"                                              \
    "v_cvt_pk_bf16_f32 v40, v52, v53\n\t"                                      \
    "v_cvt_pk_bf16_f32 v41, v54, v55\n\t"                                      \
    "v_lshlrev_b32 v52, 16, v48\n\t"                                           \
    "v_and_b32 v53, 0xffff0000, v48\n\t"                                       \
    "v_lshlrev_b32 v54, 16, v49\n\t"                                           \
    "v_and_b32 v55, 0xffff0000, v49\n\t"                                       \
    "v_mul_f32 v52, v36, v52\n\t"                                              \
    "v_mul_f32 v53, v37, v53\n\t"                                              \
    "v_mul_f32 v54, v38, v54\n\t"                                              \
    "v_mul_f32 v55, v39, v55\n\t"                                              \
    "v_cvt_pk_bf16_f32 v42, v52, v53\n\t"                                      \
    "v_cvt_pk_bf16_f32 v43, v54, v55\n\t"                                      \
    "s_nop 1\n\t"                                                              \
    "v_mfma_f32_16x16x16_bf16 v[32:35], v[56:57], v[40:41], v[58:61]\n\t"      \
    "v_mfma_f32_16x16x16_bf16 v[36:39], v[56:57], v[42:43], v[58:61]\n\t"      \
    "v_lshlrev_b32 v52, 16, v46\n\t"                                           \
    "v_and_b32 v53, 0xffff0000, v46\n\t"                                       \
    "v_lshlrev_b32 v54, 16, v47\n\t"                                           \
    "v_and_b32 v55, 0xffff0000, v47\n\t"                                       \
    "s_nop 6\n\t"                                                              \
    "v_mul_f32 v52, v32, v52\n\t"                                              \
    "v_mul_f32 v53, v33, v53\n\t"                                              \
    "v_mul_f32 v54, v34, v54\n\t"                                              \
    "v_mul_f32 v55, v35, v55\n\t"                                              \
    "v_cvt_pk_bf16_f32 v40, v52, v53\n\t"                                      \
    "v_cvt_pk_bf16_f32 v41, v54, v55\n\t"                                      \
    "v_lshlrev_b32 v52, 16, v50\n\t"                                           \
    "v_and_b32 v53, 0xffff0000, v50\n\t"                                       \
    "v_lshlrev_b32 v54, 16, v51\n\t"                                           \
    "v_and_b32 v55, 0xffff0000, v51\n\t"                                       \
    "v_mul_f32 v52, v36, v52\n\t"                                              \
    "v_mul_f32 v53, v37, v53\n\t"                                              \
    "v_mul_f32 v54, v38, v54\n\t"                                              \
    "v_mul_f32 v55, v39, v55\n\t"                                              \
    "v_cvt_pk_bf16_f32 v42, v52, v53\n\t"                                      \
    "v_cvt_pk_bf16_f32 v43, v54, v55\n\t"                                      \
    "s_sub_u32 %[cnt], %[cnt], 1\n\t"                                          \
    "s_cmp_lg_u32 %[cnt], 0\n\t"                                               \
    "s_cbranch_scc1 .LP%=\n\t"                                                 \
    "v_mov_b32 %[b0x], v40\n\t"                                                \
    "v_mov_b32 %[b0y], v41\n\t"                                                \
    "v_mov_b32 %[b1x], v42\n\t"                                                \
    "v_mov_b32 %[b1y], v43"                                                    \
    : [a0]"+v"(A0), [a1]"+v"(A1), [cnt]"+s"(CNT),                              \
      [b0x]"+v"(B0X), [b0y]"+v"(B0Y), [b1x]"+v"(B1X), [b1y]"+v"(B1Y)           \
    : [elo]"v"(ELO), [ehi]"v"(EHI)                                             \
    : "memory",                                                                \
      "v32","v33","v34","v35","v36","v37","v38","v39",                         \
      "v40","v41","v42","v43","v44","v45","v46","v47",                         \
      "v48","v49","v50","v51","v52","v53","v54","v55",                         \
      "v56","v57","v58","v59","v60","v61")

__global__ __launch_bounds__(256) void k_zero(float* lenw, float* Sw, float* out){
  int i = blockIdx.x*256 + threadIdx.x;
  if (i < Bsz) lenw[i] = 0.f;
  else if (i < 2*Bsz) Sw[i - Bsz] = 0.f;
  if (i == 0) out[0] = 0.f;
}

// lengths[b] = sum_t mask[t,b]; S[b] partial = sum_t trans[y0[t+1],y0[t]]*mask[t]
__global__ __launch_bounds__(256) void k_score(const int* __restrict__ y0,
    const float* __restrict__ mask, const float* __restrict__ trans,
    float* __restrict__ lenw, float* __restrict__ Sw){
  __shared__ float Tt[256];
  Tt[threadIdx.x] = trans[threadIdx.x];
  __syncthreads();
  int gid = blockIdx.x*256 + threadIdx.x;   // 65536 threads: b fast, tc slow
  int b  = gid & (Bsz-1);
  int tc = gid >> 11;                        // 0..31, 32 t's each
  int t0 = tc * 32;
  float lacc = 0.f, sacc = 0.f;
  int yc = y0[t0*Bsz + b];
  #pragma unroll 4
  for (int t = t0; t < t0+32; ++t) {
    float m = mask[t*Bsz + b];
    int yn = y0[(t+1)*Bsz + b];
    lacc += m;
    if (t <= Lsz-2) sacc += m * Tt[yn*16 + yc];
    yc = yn;
  }
  atomicAdd(&lenw[b], lacc);
  atomicAdd(&Sw[b], sacc);
}

// Phase 1: wave wid = bid*4+warp; cpair = wid>>11 (0..7), b = wid&2047.
// Chain0 = chunk cpair (always 64 steps: len>=512), chain1 = chunk cpair+8.
__global__ __launch_bounds__(256) void k_phase1(const float* __restrict__ h,
    const float* __restrict__ trans, const float* __restrict__ lenw,
    u32x2* __restrict__ Pout){
  // bf16 g tiles: gbuf[warp][chain][grp*132 + t*2 + half]; u32 = (tag 4g+2h,
  // tag 4g+2h+1) at time t. Row stride 132 u32 (528B, 16B-aligned; b128 reads
  // by grp hit 16 distinct banks, broadcast within grp -> conflict-free).
  __shared__ __align__(16) u32 gbuf[4][2][4*132];
  int warp = threadIdx.x >> 6;
  int wid  = blockIdx.x*4 + warp;
  int cpair= wid >> 11;          // 0..7
  int b    = wid & (Bsz-1);
  int lane = threadIdx.x & 63;
  int cl   = lane & 15;          // A-row / B-col / D-col
  int grp  = lane >> 4;          // 0..3
  int len  = (int)(lenw[b] + 0.5f);
  int t0a  = cpair << 6;         // chain0 start (always 64 active)
  int t0b  = 512 + (cpair << 6); // chain1 start
  int a1   = len - t0b;
  a1 = a1 < 0 ? 0 : (a1 > 64 ? 64 : a1);

  // ---- stage g = exp(sigmoid(h)), bf16-paired. lane -> (trow=lane>>3,
  // m=lane&7): tags {2m,2m+1}, t = trow+8k. float2 load = 8B dense.
  {
    int m = lane & 7, trow = lane >> 3;
    #pragma unroll
    for (int cc = 0; cc < 2; ++cc) {
      if (cc == 1 && a1 <= 0) break;
      int tt0 = cc ? t0b : t0a;
      const float* hp = h + (size_t)tt0*BT + b*16 + 2*m;
      u32* wp = &gbuf[warp][cc][(m>>1)*132 + (m&1)];
      #pragma unroll
      for (int k = 0; k < 8; ++k) {
        int t = trow + 8*k;
        float2 hv = *(const float2*)&hp[(size_t)t*BT];
        float g0 = exp2x(rcpx(1.f + exp2x(hv.x * (-LOG2E))) * LOG2E);
        float g1 = exp2x(rcpx(1.f + exp2x(hv.y * (-LOG2E))) * LOG2E);
        wp[2*t] = cvtpk_bf16(g0, g1);
      }
    }
  }

  // EA = E row cl, k-cols grp*4..+3, scaled 2^-4, bf16 (2 words).
  u32 elo, ehi;
  {
    const float* tp = trans + cl*16 + grp*4;
    float E0 = exp2x(tp[0]*LOG2E) * 0.0625f;
    float E1 = exp2x(tp[1]*LOG2E) * 0.0625f;
    float E2 = exp2x(tp[2]*LOG2E) * 0.0625f;
    float E3 = exp2x(tp[3]*LOG2E) * 0.0625f;
    elo = cvtpk_bf16(E0, E1);
    ehi = cvtpk_bf16(E2, E3);
  }

  int k0 = grp*4;
  u32 ibx = ((k0+0)==cl ? 0x3F80u : 0u) | (((k0+1)==cl ? 0x3F80u : 0u) << 16);
  u32 iby = ((k0+2)==cl ? 0x3F80u : 0u) | (((k0+3)==cl ? 0x3F80u : 0u) << 16);
  u32 b0x = ibx, b0y = iby, b1x = ibx, b1y = iby;

  u32 a0 = (u32)(unsigned long long)&gbuf[warp][0][grp*132];
  u32 a1a= (u32)(unsigned long long)&gbuf[warp][1][grp*132];

  int p = a1 >> 1;               // dual-step iters with chain1 live
  int odd = a1 & 1;

  if (p > 0) {
    u32 cnt = (u32)__builtin_amdgcn_readfirstlane(p);
    RUN_SEG(cnt, a0, a1a, b0x, b0y, b1x, b1y, elo, ehi);
  }

  // chain1 odd tail step (t = 2p) in C, then freeze chain1 result.
  if (odd) {
    u32x2 gw = *(const u32x2*)&gbuf[warp][1][grp*132 + 4*p];
    float f0 = __uint_as_float(gw.x << 16);
    float f1 = __uint_as_float(gw.x & 0xffff0000u);
    float f2 = __uint_as_float(gw.y << 16);
    float f3 = __uint_as_float(gw.y & 0xffff0000u);
    union { u32 u[2]; s16x4 v; } EAv, Bf;
    EAv.u[0] = elo; EAv.u[1] = ehi;
    Bf.u[0] = b1x; Bf.u[1] = b1y;
    const f32x4 z4 = {0.f,0.f,0.f,0.f};
    f32x4 d = mfma16(EAv.v, Bf.v, z4);
    b1x = cvtpk_bf16(d.x*f0, d.y*f1);
    b1y = cvtpk_bf16(d.z*f2, d.w*f3);
  }
  u32 p1x = b1x, p1y = b1y;      // chain1 final (seg2 trashes b1x/b1y)

  // chain0 remaining (64-2p) steps; chain1 slots run harmless garbage.
  if (p < 32) {
    u32 cnt = (u32)__builtin_amdgcn_readfirstlane(32 - p);
    RUN_SEG(cnt, a0, a1a, b0x, b0y, b1x, b1y, elo, ehi);
  }

  Pout[(size_t)(b*16 + cpair)*64 + lane] = (u32x2){b0x, b0y};
  if (a1 > 0)
    Pout[(size_t)(b*16 + cpair + 8)*64 + lane] = (u32x2){p1x, p1y};
}

// Phase 2: wave per b. v <- P_c * v with power-of-2 renorm; then final lse.
__global__ __launch_bounds__(256) void k_phase2(const u32x2* __restrict__ P,
    const float* __restrict__ trans, const float* __restrict__ lenw,
    const float* __restrict__ Sw, const int* __restrict__ y0,
    float* __restrict__ out){
  __shared__ float red[4];
  int b = blockIdx.x*4 + (threadIdx.x >> 6);
  int lane = threadIdx.x & 63;
  int cl = lane & 15, grp = lane >> 4;
  int len = (int)(lenw[b] + 0.5f);
  float v = (cl == 1) ? 1.f : 0.f;    // exp(Z0): one-hot at SOS_IDX=1
  float lsc = 0.f;                    // accumulated log2 scale
  int nch = (len + 63) >> 6;
  const u32x2* Pb = P + (size_t)b*16*64;
  int srcaddr = (cl >> 2) << 6;       // bpermute byte addr of lane (cl>>2)*16
  int msel = cl & 3;
  for (int c = 0; c < nch; ++c) {
    u32x2 pw = Pb[c*64 + lane];       // P[grp*4+m, cl] bf16 pairs
    float p0 = __uint_as_float(pw.x << 16);
    float p1 = __uint_as_float(pw.x & 0xffff0000u);
    float p2 = __uint_as_float(pw.y << 16);
    float p3 = __uint_as_float(pw.y & 0xffff0000u);
    float q0 = p0*v, q1 = p1*v, q2 = p2*v, q3 = p3*v;
    #pragma unroll
    for (int mk = 1; mk <= 8; mk <<= 1) {
      q0 += __shfl_xor(q0, mk);
      q1 += __shfl_xor(q1, mk);
      q2 += __shfl_xor(q2, mk);
      q3 += __shfl_xor(q3, mk);
    }
    float t0v = __int_as_float(__builtin_amdgcn_ds_bpermute(srcaddr, __float_as_int(q0)));
    float t1v = __int_as_float(__builtin_amdgcn_ds_bpermute(srcaddr, __float_as_int(q1)));
    float t2v = __int_as_float(__builtin_amdgcn_ds_bpermute(srcaddr, __float_as_int(q2)));
    float t3v = __int_as_float(__builtin_amdgcn_ds_bpermute(srcaddr, __float_as_int(q3)));
    float vn = (msel==0) ? t0v : (msel==1) ? t1v : (msel==2) ? t2v : t3v;
    float gm = fmaxf(fmaxf(q0,q1), fmaxf(q2,q3));
    gm = fmaxf(gm, __shfl_xor(gm, 16));
    gm = fmaxf(gm, __shfl_xor(gm, 32));
    int eb = (int)((__float_as_uint(gm) >> 23) & 0xff) - 127;
    float sc = __uint_as_float((u32)(127 - eb) << 23);
    v = vn * sc;
    lsc += (float)eb;
  }
  float eE = exp2x(trans[32 + cl] * LOG2E);
  float num = v * eE;
  num += __shfl_xor(num, 1);
  num += __shfl_xor(num, 2);
  num += __shfl_xor(num, 4);
  num += __shfl_xor(num, 8);
  if (lane == 0) {
    float Z = (log2x(num) + lsc + 4.f*(float)len) * LN2;
    int lastTag = y0[(size_t)len*Bsz + b];
    float Sb = Sw[b] + trans[lastTag];     // trans[PAD=0, lastTag]
    red[threadIdx.x >> 6] = (Z - Sb) * (1.f/(float)Bsz);
  }
  __syncthreads();
  if (threadIdx.x == 0) {
    atomicAdd(out, red[0] + red[1] + red[2] + red[3]);
  }
}

extern "C" void kernel_launch(void* const* d_in, const int* in_sizes, int n_in,
                              void* d_out, int out_size, void* d_ws, size_t ws_size,
                              hipStream_t stream) {
  const float* h     = (const float*)d_in[0];
  const int*   y0    = (const int*)d_in[1];
  const float* mask  = (const float*)d_in[2];
  const float* trans = (const float*)d_in[3];
  float* out  = (float*)d_out;
  float* lenw = (float*)d_ws;
  float* Sw   = lenw + Bsz;
  u32x2* P    = (u32x2*)((char*)d_ws + 16384);

  k_zero  <<<16,   256, 0, stream>>>(lenw, Sw, out);
  k_score <<<256,  256, 0, stream>>>(y0, mask, trans, lenw, Sw);
  k_phase1<<<4096, 256, 0, stream>>>(h, trans, lenw, P);
  k_phase2<<<512,  256, 0, stream>>>(P, trans, lenw, Sw, y0, out);
}